// Round 3
// baseline (208.344 us; speedup 1.0000x reference)
//
#include <hip/hip_runtime.h>

// Problem constants (from reference setup_inputs)
#define NU 100000
#define NI 100000
#define DD 64
#define LL 50
#define NB 4096
#define NT 100

#define ESTRIDE 68   // LDS row stride for E: 68*4B = 272B = 16B-aligned; 68%32=4 -> column reads conflict-free

__device__ __forceinline__ float sigmoidf_(float x) {
    return 1.0f / (1.0f + __expf(-x));
}

// ---------------------------------------------------------------------------
// One block per batch row b. 256 threads = 4 waves. All fp32.
//
//  Phase A: gather user emb (64) + item rows E[50][64] -> LDS
//  Phase B: wave0: ufg[d] = u@Wu^T + bu[d] + bi[d] ; wave1: t2[l] = u@igu ;
//           wave2: ssum[d] = sum_l E[l][d]
//  Phase C: lane=d; per l (strided by wave): pre = E[l]·Wi[d] + ufg[d];
//           gate=sig(pre); gated=E[l][d]*gate; t1=Σ_d gated*igi[d] (shfl);
//           inst=sig(t1+t2[l]); unum[d]+=gated*inst; isum+=inst.
//           Combine wave partials in LDS. v[d]=u[d]+unum[d]/isum+ssum[d].
//  Phase D: 8 lanes per (b,t): out[b,t] = b2[id] + W2[id]·v
// ---------------------------------------------------------------------------
__global__ __launch_bounds__(256) void hgn_fused(
    const int* __restrict__ user_ids,
    const int* __restrict__ item_seq_ids,
    const int* __restrict__ target_ids,
    const float* __restrict__ user_table,
    const float* __restrict__ item_table,
    const float* __restrict__ W2_table,
    const float* __restrict__ b2_table,
    const float* __restrict__ fg_item_W,
    const float* __restrict__ fg_item_b,
    const float* __restrict__ fg_user_W,
    const float* __restrict__ fg_user_b,
    const float* __restrict__ igi,
    const float* __restrict__ igu,
    float* __restrict__ out)
{
    const int b = blockIdx.x;
    const int tid = threadIdx.x;
    const int w = tid >> 6, lane = tid & 63;

    __shared__ float su[DD];               // user emb
    __shared__ float sE[LL * ESTRIDE];     // item embs
    __shared__ float sufg[DD];             // u@Wu^T + biases
    __shared__ float st2[DD];              // term2 (l<50 used)
    __shared__ float ssum[DD];             // sum_l E[l][d]
    __shared__ float spart[4 * DD];        // union numerator partials per wave
    __shared__ float sisum[4];             // inst-sum partials per wave
    __shared__ float sv[DD];               // final per-b vector

    // ---- Phase A: gathers (float4 = 16B loads/stores) ----
    const int uid = user_ids[b];
    if (tid < DD / 4)
        *(float4*)&su[tid * 4] = *(const float4*)(user_table + (size_t)uid * DD + tid * 4);
    const int* iid = item_seq_ids + b * LL;
    for (int idx = tid; idx < LL * 16; idx += 256) {       // 16 float4 per row
        const int l = idx >> 4, k4 = idx & 15;
        float4 v = *(const float4*)(item_table + (size_t)iid[l] * DD + k4 * 4);
        *(float4*)&sE[l * ESTRIDE + k4 * 4] = v;
    }
    __syncthreads();

    // ---- Phase B: small matvecs ----
    if (w == 0) {
        const int d = lane;
        float acc = fg_user_b[d] + fg_item_b[d];
#pragma unroll
        for (int c4 = 0; c4 < 16; c4++) {
            float4 wr = *(const float4*)(fg_user_W + d * DD + c4 * 4);
            acc += wr.x * su[c4 * 4 + 0] + wr.y * su[c4 * 4 + 1]
                 + wr.z * su[c4 * 4 + 2] + wr.w * su[c4 * 4 + 3];
        }
        sufg[d] = acc;
    } else if (w == 1) {
        const int l = lane;
        if (l < LL) {
            float acc = 0.f;
#pragma unroll 8
            for (int k = 0; k < DD; k++) acc += su[k] * igu[k * LL + l];
            st2[l] = acc;
        }
    } else if (w == 2) {
        const int d = lane;
        float s = 0.f;
#pragma unroll
        for (int l = 0; l < LL; l++) s += sE[l * ESTRIDE + d];
        ssum[d] = s;
    }
    __syncthreads();

    // ---- Phase C: gate matmul + union (all 4 waves, l strided by wave) ----
    const int d = lane;
    float wi[DD];
#pragma unroll
    for (int c4 = 0; c4 < 16; c4++) {
        float4 wr = *(const float4*)(fg_item_W + d * DD + c4 * 4);
        wi[c4 * 4 + 0] = wr.x; wi[c4 * 4 + 1] = wr.y;
        wi[c4 * 4 + 2] = wr.z; wi[c4 * 4 + 3] = wr.w;
    }
    const float igid = igi[d];

    float unum = 0.f, isump = 0.f;
    for (int i = 0; i < 13; i++) {
        const int l = w + 4 * i;               // wave-uniform
        if (l < LL) {
            const float* e = &sE[l * ESTRIDE];
            float pre = sufg[d];
#pragma unroll
            for (int k = 0; k < DD; k++) pre += e[k] * wi[k];
            const float gate = sigmoidf_(pre);
            const float gated = e[d] * gate;
            float t1 = gated * igid;
            t1 += __shfl_xor(t1, 1);  t1 += __shfl_xor(t1, 2);
            t1 += __shfl_xor(t1, 4);  t1 += __shfl_xor(t1, 8);
            t1 += __shfl_xor(t1, 16); t1 += __shfl_xor(t1, 32);
            const float inst = sigmoidf_(t1 + st2[l]);
            unum += gated * inst;
            isump += inst;                     // wave-uniform
        }
    }
    spart[w * DD + d] = unum;
    if (lane == 0) sisum[w] = isump;
    __syncthreads();

    if (w == 0) {
        const float num = spart[d] + spart[DD + d] + spart[2 * DD + d] + spart[3 * DD + d];
        const float den = sisum[0] + sisum[1] + sisum[2] + sisum[3];
        sv[d] = su[d] + num / den + ssum[d];
    }
    __syncthreads();

    // ---- Phase D: scores. 8 lanes per (b,t), each lane covers 8 dims ----
    const int j = tid & 7, g = tid >> 3;       // 32 groups of 8 lanes
    float vreg[8];
#pragma unroll
    for (int i = 0; i < 8; i++) vreg[i] = sv[j * 8 + i];

#pragma unroll
    for (int it = 0; it < 4; it++) {
        const int t = it * 32 + g;
        if (t < NT) {
            const int id = target_ids[b * NT + t];
            const float* wrow = W2_table + (size_t)id * DD + j * 8;
            float4 w0 = *(const float4*)(wrow);
            float4 w1 = *(const float4*)(wrow + 4);
            float s = w0.x * vreg[0] + w0.y * vreg[1] + w0.z * vreg[2] + w0.w * vreg[3]
                    + w1.x * vreg[4] + w1.y * vreg[5] + w1.z * vreg[6] + w1.w * vreg[7];
            s += __shfl_xor(s, 1);
            s += __shfl_xor(s, 2);
            s += __shfl_xor(s, 4);
            if (j == 0) out[b * NT + t] = s + b2_table[id];
        }
    }
}

// ---------------------------------------------------------------------------
extern "C" void kernel_launch(void* const* d_in, const int* in_sizes, int n_in,
                              void* d_out, int out_size, void* d_ws, size_t ws_size,
                              hipStream_t stream)
{
    const int* user_ids        = (const int*)d_in[0];
    const int* item_seq_ids    = (const int*)d_in[1];
    const int* target_item_ids = (const int*)d_in[2];
    const float* user_tab      = (const float*)d_in[3];
    const float* item_tab      = (const float*)d_in[4];
    const float* W2_tab        = (const float*)d_in[5];
    const float* b2_tab        = (const float*)d_in[6];
    const float* fg_item_W     = (const float*)d_in[7];
    const float* fg_item_b     = (const float*)d_in[8];
    const float* fg_user_W     = (const float*)d_in[9];
    const float* fg_user_b     = (const float*)d_in[10];
    const float* igi           = (const float*)d_in[11];
    const float* igu           = (const float*)d_in[12];
    float* out = (float*)d_out;

    hgn_fused<<<NB, 256, 0, stream>>>(user_ids, item_seq_ids, target_item_ids,
                                      user_tab, item_tab, W2_tab, b2_tab,
                                      fg_item_W, fg_item_b, fg_user_W, fg_user_b,
                                      igi, igu, out);
}

// Round 4
// 186.174 us; speedup vs baseline: 1.1191x; 1.1191x over previous
//
#include <hip/hip_runtime.h>

// Problem constants
#define DD 64
#define LL 50
#define NB 4096
#define NT 100
#define ES 68   // sE row stride (f32): 272 B = 16B-aligned; epilogue col reads (16q+c)%32 -> 2-way (free)

typedef __attribute__((ext_vector_type(8))) __bf16 bf16x8;
typedef __attribute__((ext_vector_type(4))) float f32x4;

__device__ __forceinline__ float sigmoidf_(float x) {
    return 1.0f / (1.0f + __expf(-x));
}
// round-half-up f32->bf16, pack two into one u32 (hi -> upper 16)
__device__ __forceinline__ unsigned pack_bf16(float hi, float lo) {
    union { float f; unsigned u; } a, b;
    a.f = hi; b.f = lo;
    return ((a.u + 0x8000u) & 0xffff0000u) | ((b.u + 0x8000u) >> 16);
}
__device__ __forceinline__ bf16x8 cvt8(const float* f) {
    uint4 r;
    r.x = pack_bf16(f[1], f[0]);
    r.y = pack_bf16(f[3], f[2]);
    r.z = pack_bf16(f[5], f[4]);
    r.w = pack_bf16(f[7], f[6]);
    return __builtin_bit_cast(bf16x8, r);
}

// ---------------------------------------------------------------------------
// One block per b, 4 waves. Wave w owns m-tile mi=w (l = 16w .. 16w+15).
//  - E gather -> LDS (f32, epilogue only). A/B MFMA frags loaded from global
//    (L1-hot) and rounded to bf16. Gate preact via 8 MFMAs/wave.
//  - Phase B: wave0 ufg[d]=u@Wu^T+bu+bi, wave1 t2[l]=u@igu (f32 VALU).
//  - Epilogue in MFMA C-layout (col=lane&15, row=(lane>>4)*4+reg):
//    gate/gated/t1 (shfl over c) /inst/unum/sip (shfl over q), partials in LDS.
//  - v[d] = u[d] + unum/isum + ssum;  Phase D: 8 lanes per (b,t) W2 dot.
// ---------------------------------------------------------------------------
__global__ __launch_bounds__(256) void hgn_fused(
    const int* __restrict__ user_ids,
    const int* __restrict__ item_seq_ids,
    const int* __restrict__ target_ids,
    const float* __restrict__ user_table,
    const float* __restrict__ item_table,
    const float* __restrict__ W2_table,
    const float* __restrict__ b2_table,
    const float* __restrict__ fg_item_W,
    const float* __restrict__ fg_item_b,
    const float* __restrict__ fg_user_W,
    const float* __restrict__ fg_user_b,
    const float* __restrict__ igi,
    const float* __restrict__ igu,
    float* __restrict__ out)
{
    const int b = blockIdx.x;
    const int tid = threadIdx.x;
    const int w = tid >> 6, lane = tid & 63;
    const int c = lane & 15, q = lane >> 4;

    __shared__ float sE[LL * ES];
    __shared__ float sufg[DD];
    __shared__ float st2[DD];
    __shared__ float spart[4 * DD];
    __shared__ float ssump[4 * DD];
    __shared__ float sisum[4];
    __shared__ float sv[DD];

    const int* iid = item_seq_ids + b * LL;
    const int uid = user_ids[b];

    // ---- E gather: 50 rows x 8 chunks of 8 floats ----
    for (int s = tid; s < LL * 8; s += 256) {
        const int l = s >> 3, ch = s & 7;
        const float* src = item_table + (size_t)iid[l] * DD + ch * 8;
        float4 v0 = *(const float4*)src;
        float4 v1 = *(const float4*)(src + 4);
        *(float4*)&sE[l * ES + ch * 8] = v0;
        *(float4*)&sE[l * ES + ch * 8 + 4] = v1;
    }

    // ---- Phase B ----
    if (w == 0) {
        const int d = lane;
        float acc = fg_user_b[d] + fg_item_b[d];
#pragma unroll
        for (int k4 = 0; k4 < 16; k4++) {
            float4 wr = *(const float4*)(fg_user_W + d * DD + k4 * 4);
            float4 uk = *(const float4*)(user_table + (size_t)uid * DD + k4 * 4); // uniform
            acc += wr.x * uk.x + wr.y * uk.y + wr.z * uk.z + wr.w * uk.w;
        }
        sufg[d] = acc;
    } else if (w == 1) {
        const int l = lane;
        float acc = 0.f;
        if (l < LL) {
#pragma unroll 16
            for (int k = 0; k < DD; k++)
                acc += user_table[(size_t)uid * DD + k] * igu[k * LL + l];
        }
        st2[lane] = acc;
    }

    // ---- B-frags: Wi rows (n = 16ni + c, k = kf*32 + q*8 + j) ----
    bf16x8 wb[4][2];
#pragma unroll
    for (int ni = 0; ni < 4; ni++) {
#pragma unroll
        for (int kf = 0; kf < 2; kf++) {
            float tmp[8];
            const float* src = fg_item_W + (ni * 16 + c) * DD + kf * 32 + q * 8;
            *(float4*)&tmp[0] = *(const float4*)src;
            *(float4*)&tmp[4] = *(const float4*)(src + 4);
            wb[ni][kf] = cvt8(tmp);
        }
    }
    // ---- A-frags: item row l = 16w + c, k = kf*32 + q*8 + j ----
    bf16x8 ea[2];
    {
        float tmp[16];
        const int la = w * 16 + c;
        if (la < LL) {
            const float* src = item_table + (size_t)iid[la] * DD;
            *(float4*)&tmp[0]  = *(const float4*)(src + q * 8);
            *(float4*)&tmp[4]  = *(const float4*)(src + q * 8 + 4);
            *(float4*)&tmp[8]  = *(const float4*)(src + 32 + q * 8);
            *(float4*)&tmp[12] = *(const float4*)(src + 32 + q * 8 + 4);
        } else {
#pragma unroll
            for (int i = 0; i < 16; i++) tmp[i] = 0.f;
        }
        ea[0] = cvt8(tmp);
        ea[1] = cvt8(tmp + 8);
    }

    // ---- MFMA: acc[ni] = E-tile(mi=w) @ Wi^T-tile(ni) ----
    f32x4 acc[4];
#pragma unroll
    for (int ni = 0; ni < 4; ni++) {
        f32x4 a = {0.f, 0.f, 0.f, 0.f};
        a = __builtin_amdgcn_mfma_f32_16x16x32_bf16(ea[0], wb[ni][0], a, 0, 0, 0);
        a = __builtin_amdgcn_mfma_f32_16x16x32_bf16(ea[1], wb[ni][1], a, 0, 0, 0);
        acc[ni] = a;
    }
    __syncthreads();   // sE, sufg, st2 ready

    // ---- Epilogue (C layout: l = 16w + 4q + reg, d = 16ni + c) ----
    float ufg4[4], igi4[4];
#pragma unroll
    for (int ni = 0; ni < 4; ni++) {
        ufg4[ni] = sufg[ni * 16 + c];
        igi4[ni] = igi[ni * 16 + c];
    }

    float gated[4][4];    // [reg][ni]
    float inst_r[4];
    float unum[4] = {0.f, 0.f, 0.f, 0.f};   // per ni
    float sip[4]  = {0.f, 0.f, 0.f, 0.f};
#pragma unroll
    for (int reg = 0; reg < 4; reg++) {
        const int l = w * 16 + q * 4 + reg;
        const int lc = (l < LL) ? l : 0;
        const float lm = (l < LL) ? 1.f : 0.f;
        float t1 = 0.f;
#pragma unroll
        for (int ni = 0; ni < 4; ni++) {
            const float e = sE[lc * ES + ni * 16 + c] * lm;
            const float g = sigmoidf_(acc[ni][reg] + ufg4[ni]);
            const float gd = e * g;
            gated[reg][ni] = gd;
            t1 += gd * igi4[ni];
            sip[ni] += e;
        }
        t1 += __shfl_xor(t1, 1); t1 += __shfl_xor(t1, 2);
        t1 += __shfl_xor(t1, 4); t1 += __shfl_xor(t1, 8);
        inst_r[reg] = (l < LL) ? sigmoidf_(t1 + st2[lc]) : 0.f;
    }

    float isum = inst_r[0] + inst_r[1] + inst_r[2] + inst_r[3];
#pragma unroll
    for (int ni = 0; ni < 4; ni++)
#pragma unroll
        for (int reg = 0; reg < 4; reg++)
            unum[ni] += gated[reg][ni] * inst_r[reg];

#pragma unroll
    for (int ni = 0; ni < 4; ni++) {
        unum[ni] += __shfl_xor(unum[ni], 16); unum[ni] += __shfl_xor(unum[ni], 32);
        sip[ni]  += __shfl_xor(sip[ni], 16);  sip[ni]  += __shfl_xor(sip[ni], 32);
    }
    isum += __shfl_xor(isum, 16); isum += __shfl_xor(isum, 32);

    // lane writes slot d = 16q + c = lane, taking its ni == q partial
    const float un = (q == 0) ? unum[0] : (q == 1) ? unum[1] : (q == 2) ? unum[2] : unum[3];
    const float si = (q == 0) ? sip[0]  : (q == 1) ? sip[1]  : (q == 2) ? sip[2]  : sip[3];
    spart[w * DD + lane] = un;
    ssump[w * DD + lane] = si;
    if (lane == 0) sisum[w] = isum;
    __syncthreads();

    if (w == 0) {
        const int d = lane;
        const float num = spart[d] + spart[DD + d] + spart[2 * DD + d] + spart[3 * DD + d];
        const float ss  = ssump[d] + ssump[DD + d] + ssump[2 * DD + d] + ssump[3 * DD + d];
        const float den = sisum[0] + sisum[1] + sisum[2] + sisum[3];
        sv[d] = user_table[(size_t)uid * DD + d] + num / den + ss;
    }
    __syncthreads();

    // ---- Phase D: scores. 8 lanes per (b,t) ----
    const int j = tid & 7, g = tid >> 3;
    float vreg[8];
#pragma unroll
    for (int i = 0; i < 8; i++) vreg[i] = sv[j * 8 + i];

#pragma unroll
    for (int it = 0; it < 4; it++) {
        const int t = it * 32 + g;
        if (t < NT) {
            const int id = target_ids[b * NT + t];
            const float* wrow = W2_table + (size_t)id * DD + j * 8;
            float4 w0 = *(const float4*)(wrow);
            float4 w1 = *(const float4*)(wrow + 4);
            float s = w0.x * vreg[0] + w0.y * vreg[1] + w0.z * vreg[2] + w0.w * vreg[3]
                    + w1.x * vreg[4] + w1.y * vreg[5] + w1.z * vreg[6] + w1.w * vreg[7];
            s += __shfl_xor(s, 1);
            s += __shfl_xor(s, 2);
            s += __shfl_xor(s, 4);
            if (j == 0) out[b * NT + t] = s + b2_table[id];
        }
    }
}

// ---------------------------------------------------------------------------
extern "C" void kernel_launch(void* const* d_in, const int* in_sizes, int n_in,
                              void* d_out, int out_size, void* d_ws, size_t ws_size,
                              hipStream_t stream)
{
    const int* user_ids        = (const int*)d_in[0];
    const int* item_seq_ids    = (const int*)d_in[1];
    const int* target_item_ids = (const int*)d_in[2];
    const float* user_tab      = (const float*)d_in[3];
    const float* item_tab      = (const float*)d_in[4];
    const float* W2_tab        = (const float*)d_in[5];
    const float* b2_tab        = (const float*)d_in[6];
    const float* fg_item_W     = (const float*)d_in[7];
    const float* fg_item_b     = (const float*)d_in[8];
    const float* fg_user_W     = (const float*)d_in[9];
    const float* fg_user_b     = (const float*)d_in[10];
    const float* igi           = (const float*)d_in[11];
    const float* igu           = (const float*)d_in[12];
    float* out = (float*)d_out;

    hgn_fused<<<NB, 256, 0, stream>>>(user_ids, item_seq_ids, target_item_ids,
                                      user_tab, item_tab, W2_tab, b2_tab,
                                      fg_item_W, fg_item_b, fg_user_W, fg_user_b,
                                      igi, igu, out);
}

// Round 5
// 161.653 us; speedup vs baseline: 1.2888x; 1.1517x over previous
//
#include <hip/hip_runtime.h>

// Problem constants
#define DD 64
#define LL 50
#define NB 4096
#define NT 100
#define ES 68   // fallback kernel's f32 LDS row stride

typedef __attribute__((ext_vector_type(8))) __bf16 bf16x8;
typedef __attribute__((ext_vector_type(4))) float f32x4;

__device__ __forceinline__ float sigmoidf_(float x) {
    return 1.0f / (1.0f + __expf(-x));
}
__device__ __forceinline__ float b2f(unsigned short h) {
    union { unsigned int u; float f; } v; v.u = ((unsigned int)h) << 16; return v.f;
}
// round-half-up f32->bf16, pack two into one u32 (hi -> upper 16)
__device__ __forceinline__ unsigned pack_bf16(float hi, float lo) {
    union { float f; unsigned u; } a, b;
    a.f = hi; b.f = lo;
    return ((a.u + 0x8000u) & 0xffff0000u) | ((b.u + 0x8000u) >> 16);
}
__device__ __forceinline__ uint4 cvt8u(const float* f) {
    uint4 r;
    r.x = pack_bf16(f[1], f[0]);
    r.y = pack_bf16(f[3], f[2]);
    r.z = pack_bf16(f[5], f[4]);
    r.w = pack_bf16(f[7], f[6]);
    return r;
}
__device__ __forceinline__ bf16x8 cvt8(const float* f) {
    return __builtin_bit_cast(bf16x8, cvt8u(f));
}

// ===========================================================================
// K0: batched user GEMM. A = U[16 users x 64], B = [Wu^T (n<64) | igu (n=64+l)].
// One wave per 16 users; grid 256. ufg gets both biases folded.
// ===========================================================================
__global__ __launch_bounds__(64) void k0_user(
    const int* __restrict__ uid_g, const float* __restrict__ user_table,
    const float* __restrict__ Wu, const float* __restrict__ bu,
    const float* __restrict__ bi, const float* __restrict__ igu,
    float* __restrict__ ufg_ws, float* __restrict__ t2_ws)
{
    const int lane = threadIdx.x;
    const int c = lane & 15, q = lane >> 4;
    const int uid = uid_g[blockIdx.x * 16 + c];
    const float* urow = user_table + (size_t)uid * DD;

    bf16x8 af[2];
#pragma unroll
    for (int kf = 0; kf < 2; kf++) {
        float tmp[8];
        *(float4*)&tmp[0] = *(const float4*)(urow + kf * 32 + q * 8);
        *(float4*)&tmp[4] = *(const float4*)(urow + kf * 32 + q * 8 + 4);
        af[kf] = cvt8(tmp);
    }

#pragma unroll
    for (int ni = 0; ni < 8; ni++) {
        f32x4 a = {0.f, 0.f, 0.f, 0.f};
#pragma unroll
        for (int kf = 0; kf < 2; kf++) {
            const int k0 = kf * 32 + q * 8;
            float tmp[8];
            if (ni < 4) {
                const float* src = Wu + (ni * 16 + c) * DD + k0;
                *(float4*)&tmp[0] = *(const float4*)src;
                *(float4*)&tmp[4] = *(const float4*)(src + 4);
            } else {
                const int l = ni * 16 + c - 64;
#pragma unroll
                for (int j = 0; j < 8; j++)
                    tmp[j] = (l < LL) ? igu[(k0 + j) * LL + l] : 0.f;
            }
            a = __builtin_amdgcn_mfma_f32_16x16x32_bf16(af[kf], cvt8(tmp), a, 0, 0, 0);
        }
        const int n = ni * 16 + c;
#pragma unroll
        for (int reg = 0; reg < 4; reg++) {
            const int bo = blockIdx.x * 16 + q * 4 + reg;
            if (n < DD)           ufg_ws[bo * DD + n] = a[reg] + bu[n] + bi[n];
            else if (n < DD + LL) t2_ws[bo * DD + (n - DD)] = a[reg];
        }
    }
}

// ===========================================================================
// K1: union vector, one WAVE per b (4 b per 256-thread block), one barrier.
// Wi staged to LDS bf16 per block; E gathered to A-frags + bf16 LDS slab.
// ===========================================================================
__global__ __launch_bounds__(256) void k1_union(
    const int* __restrict__ uid_g, const int* __restrict__ iid_g,
    const float* __restrict__ user_table, const float* __restrict__ item_table,
    const float* __restrict__ Wi, const float* __restrict__ igi,
    const float* __restrict__ ufg_ws, const float* __restrict__ t2_ws,
    float* __restrict__ v_ws)
{
    const int tid = threadIdx.x;
    const int w = tid >> 6, lane = tid & 63;
    const int c = lane & 15, q = lane >> 4;
    const int b = blockIdx.x * 4 + w;

    __shared__ unsigned short sE[4][LL][72];   // bf16, row stride 72 hw (144 B)
    __shared__ unsigned short sW[DD][72];      // Wi bf16

    // stage Wi -> LDS (coalesced: 4 threads per row)
    {
        const int n = tid >> 2, ch = tid & 3;
        float tmp[16];
        const float* src = Wi + n * DD + ch * 16;
        *(float4*)&tmp[0]  = *(const float4*)(src);
        *(float4*)&tmp[4]  = *(const float4*)(src + 4);
        *(float4*)&tmp[8]  = *(const float4*)(src + 8);
        *(float4*)&tmp[12] = *(const float4*)(src + 12);
        *(uint4*)&sW[n][ch * 16]     = cvt8u(tmp);
        *(uint4*)&sW[n][ch * 16 + 8] = cvt8u(tmp + 8);
    }

    // gather E rows -> A-frags + LDS slab (wave-private)
    const int* iid = iid_g + b * LL;
    bf16x8 ea[4][2];
#pragma unroll
    for (int mi = 0; mi < 4; mi++) {
        const int l = mi * 16 + c;
        if (l < LL) {
            const float* src = item_table + (size_t)iid[l] * DD;
#pragma unroll
            for (int kf = 0; kf < 2; kf++) {
                float tmp[8];
                *(float4*)&tmp[0] = *(const float4*)(src + kf * 32 + q * 8);
                *(float4*)&tmp[4] = *(const float4*)(src + kf * 32 + q * 8 + 4);
                uint4 p = cvt8u(tmp);
                ea[mi][kf] = __builtin_bit_cast(bf16x8, p);
                *(uint4*)&sE[w][l][kf * 32 + q * 8] = p;
            }
        } else {
            uint4 z = {0u, 0u, 0u, 0u};
            ea[mi][0] = __builtin_bit_cast(bf16x8, z);
            ea[mi][1] = __builtin_bit_cast(bf16x8, z);
        }
    }
    __syncthreads();   // sW ready (sE is wave-private, also done)

    bf16x8 wb[4][2];
#pragma unroll
    for (int ni = 0; ni < 4; ni++)
#pragma unroll
        for (int kf = 0; kf < 2; kf++)
            wb[ni][kf] = __builtin_bit_cast(bf16x8,
                *(const uint4*)&sW[ni * 16 + c][kf * 32 + q * 8]);

    float ufg4[4], igi4[4];
#pragma unroll
    for (int ni = 0; ni < 4; ni++) {
        ufg4[ni] = ufg_ws[b * DD + ni * 16 + c];
        igi4[ni] = igi[ni * 16 + c];
    }

    float unum[4] = {0.f, 0.f, 0.f, 0.f};
    float sip[4]  = {0.f, 0.f, 0.f, 0.f};
    float isum = 0.f;

#pragma unroll
    for (int mi = 0; mi < 4; mi++) {
        f32x4 acc[4];
#pragma unroll
        for (int ni = 0; ni < 4; ni++) {
            f32x4 a = {0.f, 0.f, 0.f, 0.f};
            a = __builtin_amdgcn_mfma_f32_16x16x32_bf16(ea[mi][0], wb[ni][0], a, 0, 0, 0);
            a = __builtin_amdgcn_mfma_f32_16x16x32_bf16(ea[mi][1], wb[ni][1], a, 0, 0, 0);
            acc[ni] = a;
        }
        float gated[4][4], inst_r[4];
#pragma unroll
        for (int reg = 0; reg < 4; reg++) {
            const int l = mi * 16 + q * 4 + reg;
            const int valid = (l < LL);
            const int lc = valid ? l : 0;
            const float lm = valid ? 1.f : 0.f;
            float t1 = 0.f;
#pragma unroll
            for (int ni = 0; ni < 4; ni++) {
                const float e = b2f(sE[w][lc][ni * 16 + c]) * lm;
                const float g = sigmoidf_(acc[ni][reg] + ufg4[ni]);
                const float gd = e * g;
                gated[reg][ni] = gd;
                t1 += gd * igi4[ni];
                sip[ni] += e;
            }
            t1 += __shfl_xor(t1, 1); t1 += __shfl_xor(t1, 2);
            t1 += __shfl_xor(t1, 4); t1 += __shfl_xor(t1, 8);
            inst_r[reg] = valid ? sigmoidf_(t1 + t2_ws[b * DD + lc]) : 0.f;
        }
#pragma unroll
        for (int reg = 0; reg < 4; reg++) {
            isum += inst_r[reg];
#pragma unroll
            for (int ni = 0; ni < 4; ni++)
                unum[ni] += gated[reg][ni] * inst_r[reg];
        }
    }

#pragma unroll
    for (int ni = 0; ni < 4; ni++) {
        unum[ni] += __shfl_xor(unum[ni], 16); unum[ni] += __shfl_xor(unum[ni], 32);
        sip[ni]  += __shfl_xor(sip[ni], 16);  sip[ni]  += __shfl_xor(sip[ni], 32);
    }
    isum += __shfl_xor(isum, 16); isum += __shfl_xor(isum, 32);

    const float un = (q == 0) ? unum[0] : (q == 1) ? unum[1] : (q == 2) ? unum[2] : unum[3];
    const float si = (q == 0) ? sip[0]  : (q == 1) ? sip[1]  : (q == 2) ? sip[2]  : sip[3];
    const int uid = uid_g[b];
    const float u = user_table[(size_t)uid * DD + lane];
    v_ws[b * DD + lane] = u + un / isum + si;
}

// ===========================================================================
// K2: streaming scores. One block per b; 8 lanes per (b,t).
// ===========================================================================
__global__ __launch_bounds__(256) void k2_score(
    const int* __restrict__ tgt_g, const float* __restrict__ W2,
    const float* __restrict__ b2, const float* __restrict__ v_ws,
    float* __restrict__ out)
{
    const int b = blockIdx.x;
    const int tid = threadIdx.x;
    __shared__ float sv[DD];
    if (tid < DD) sv[tid] = v_ws[b * DD + tid];
    __syncthreads();

    const int j = tid & 7, g = tid >> 3;
    float vr[8];
#pragma unroll
    for (int i = 0; i < 8; i++) vr[i] = sv[j * 8 + i];

#pragma unroll
    for (int it = 0; it < 4; it++) {
        const int t = it * 32 + g;
        if (t < NT) {
            const int id = tgt_g[b * NT + t];
            const float* wrow = W2 + (size_t)id * DD + j * 8;
            float4 w0 = *(const float4*)(wrow);
            float4 w1 = *(const float4*)(wrow + 4);
            float s = w0.x * vr[0] + w0.y * vr[1] + w0.z * vr[2] + w0.w * vr[3]
                    + w1.x * vr[4] + w1.y * vr[5] + w1.z * vr[6] + w1.w * vr[7];
            s += __shfl_xor(s, 1);
            s += __shfl_xor(s, 2);
            s += __shfl_xor(s, 4);
            if (j == 0) out[b * NT + t] = s + b2[id];
        }
    }
}

// ===========================================================================
// Fallback: R4 fused kernel (used only if ws_size < 3 MB)
// ===========================================================================
__global__ __launch_bounds__(256) void hgn_fused(
    const int* __restrict__ user_ids, const int* __restrict__ item_seq_ids,
    const int* __restrict__ target_ids, const float* __restrict__ user_table,
    const float* __restrict__ item_table, const float* __restrict__ W2_table,
    const float* __restrict__ b2_table, const float* __restrict__ fg_item_W,
    const float* __restrict__ fg_item_b, const float* __restrict__ fg_user_W,
    const float* __restrict__ fg_user_b, const float* __restrict__ igi,
    const float* __restrict__ igu, float* __restrict__ out)
{
    const int b = blockIdx.x;
    const int tid = threadIdx.x;
    const int w = tid >> 6, lane = tid & 63;
    const int c = lane & 15, q = lane >> 4;

    __shared__ float sE[LL * ES];
    __shared__ float sufg[DD];
    __shared__ float st2[DD];
    __shared__ float spart[4 * DD];
    __shared__ float ssump[4 * DD];
    __shared__ float sisum[4];
    __shared__ float sv[DD];

    const int* iid = item_seq_ids + b * LL;
    const int uid = user_ids[b];

    for (int s = tid; s < LL * 8; s += 256) {
        const int l = s >> 3, ch = s & 7;
        const float* src = item_table + (size_t)iid[l] * DD + ch * 8;
        float4 v0 = *(const float4*)src;
        float4 v1 = *(const float4*)(src + 4);
        *(float4*)&sE[l * ES + ch * 8] = v0;
        *(float4*)&sE[l * ES + ch * 8 + 4] = v1;
    }

    if (w == 0) {
        const int d = lane;
        float acc = fg_user_b[d] + fg_item_b[d];
#pragma unroll
        for (int k4 = 0; k4 < 16; k4++) {
            float4 wr = *(const float4*)(fg_user_W + d * DD + k4 * 4);
            float4 uk = *(const float4*)(user_table + (size_t)uid * DD + k4 * 4);
            acc += wr.x * uk.x + wr.y * uk.y + wr.z * uk.z + wr.w * uk.w;
        }
        sufg[d] = acc;
    } else if (w == 1) {
        const int l = lane;
        float acc = 0.f;
        if (l < LL) {
#pragma unroll 16
            for (int k = 0; k < DD; k++)
                acc += user_table[(size_t)uid * DD + k] * igu[k * LL + l];
        }
        st2[lane] = acc;
    }

    bf16x8 wb[4][2];
#pragma unroll
    for (int ni = 0; ni < 4; ni++)
#pragma unroll
        for (int kf = 0; kf < 2; kf++) {
            float tmp[8];
            const float* src = fg_item_W + (ni * 16 + c) * DD + kf * 32 + q * 8;
            *(float4*)&tmp[0] = *(const float4*)src;
            *(float4*)&tmp[4] = *(const float4*)(src + 4);
            wb[ni][kf] = cvt8(tmp);
        }
    bf16x8 ea[2];
    {
        float tmp[16];
        const int la = w * 16 + c;
        if (la < LL) {
            const float* src = item_table + (size_t)iid[la] * DD;
            *(float4*)&tmp[0]  = *(const float4*)(src + q * 8);
            *(float4*)&tmp[4]  = *(const float4*)(src + q * 8 + 4);
            *(float4*)&tmp[8]  = *(const float4*)(src + 32 + q * 8);
            *(float4*)&tmp[12] = *(const float4*)(src + 32 + q * 8 + 4);
        } else {
#pragma unroll
            for (int i = 0; i < 16; i++) tmp[i] = 0.f;
        }
        ea[0] = cvt8(tmp);
        ea[1] = cvt8(tmp + 8);
    }

    f32x4 acc[4];
#pragma unroll
    for (int ni = 0; ni < 4; ni++) {
        f32x4 a = {0.f, 0.f, 0.f, 0.f};
        a = __builtin_amdgcn_mfma_f32_16x16x32_bf16(ea[0], wb[ni][0], a, 0, 0, 0);
        a = __builtin_amdgcn_mfma_f32_16x16x32_bf16(ea[1], wb[ni][1], a, 0, 0, 0);
        acc[ni] = a;
    }
    __syncthreads();

    float ufg4[4], igi4[4];
#pragma unroll
    for (int ni = 0; ni < 4; ni++) {
        ufg4[ni] = sufg[ni * 16 + c];
        igi4[ni] = igi[ni * 16 + c];
    }

    float gated[4][4], inst_r[4];
    float unum[4] = {0.f, 0.f, 0.f, 0.f};
    float sip[4]  = {0.f, 0.f, 0.f, 0.f};
#pragma unroll
    for (int reg = 0; reg < 4; reg++) {
        const int l = w * 16 + q * 4 + reg;
        const int lc = (l < LL) ? l : 0;
        const float lm = (l < LL) ? 1.f : 0.f;
        float t1 = 0.f;
#pragma unroll
        for (int ni = 0; ni < 4; ni++) {
            const float e = sE[lc * ES + ni * 16 + c] * lm;
            const float g = sigmoidf_(acc[ni][reg] + ufg4[ni]);
            const float gd = e * g;
            gated[reg][ni] = gd;
            t1 += gd * igi4[ni];
            sip[ni] += e;
        }
        t1 += __shfl_xor(t1, 1); t1 += __shfl_xor(t1, 2);
        t1 += __shfl_xor(t1, 4); t1 += __shfl_xor(t1, 8);
        inst_r[reg] = (l < LL) ? sigmoidf_(t1 + st2[lc]) : 0.f;
    }

    float isum = inst_r[0] + inst_r[1] + inst_r[2] + inst_r[3];
#pragma unroll
    for (int ni = 0; ni < 4; ni++)
#pragma unroll
        for (int reg = 0; reg < 4; reg++)
            unum[ni] += gated[reg][ni] * inst_r[reg];

#pragma unroll
    for (int ni = 0; ni < 4; ni++) {
        unum[ni] += __shfl_xor(unum[ni], 16); unum[ni] += __shfl_xor(unum[ni], 32);
        sip[ni]  += __shfl_xor(sip[ni], 16);  sip[ni]  += __shfl_xor(sip[ni], 32);
    }
    isum += __shfl_xor(isum, 16); isum += __shfl_xor(isum, 32);

    const float un = (q == 0) ? unum[0] : (q == 1) ? unum[1] : (q == 2) ? unum[2] : unum[3];
    const float si = (q == 0) ? sip[0]  : (q == 1) ? sip[1]  : (q == 2) ? sip[2]  : sip[3];
    spart[w * DD + lane] = un;
    ssump[w * DD + lane] = si;
    if (lane == 0) sisum[w] = isum;
    __syncthreads();

    if (w == 0) {
        const int d = lane;
        const float num = spart[d] + spart[DD + d] + spart[2 * DD + d] + spart[3 * DD + d];
        const float ss  = ssump[d] + ssump[DD + d] + ssump[2 * DD + d] + ssump[3 * DD + d];
        const float den = sisum[0] + sisum[1] + sisum[2] + sisum[3];
        sv[d] = user_table[(size_t)uid * DD + d] + num / den + ss;
    }
    __syncthreads();

    const int j = tid & 7, g = tid >> 3;
    float vr[8];
#pragma unroll
    for (int i = 0; i < 8; i++) vr[i] = sv[j * 8 + i];
#pragma unroll
    for (int it = 0; it < 4; it++) {
        const int t = it * 32 + g;
        if (t < NT) {
            const int id = target_ids[b * NT + t];
            const float* wrow = W2_table + (size_t)id * DD + j * 8;
            float4 w0 = *(const float4*)(wrow);
            float4 w1 = *(const float4*)(wrow + 4);
            float s = w0.x * vr[0] + w0.y * vr[1] + w0.z * vr[2] + w0.w * vr[3]
                    + w1.x * vr[4] + w1.y * vr[5] + w1.z * vr[6] + w1.w * vr[7];
            s += __shfl_xor(s, 1);
            s += __shfl_xor(s, 2);
            s += __shfl_xor(s, 4);
            if (j == 0) out[b * NT + t] = s + b2_table[id];
        }
    }
}

// ===========================================================================
extern "C" void kernel_launch(void* const* d_in, const int* in_sizes, int n_in,
                              void* d_out, int out_size, void* d_ws, size_t ws_size,
                              hipStream_t stream)
{
    const int* user_ids        = (const int*)d_in[0];
    const int* item_seq_ids    = (const int*)d_in[1];
    const int* target_item_ids = (const int*)d_in[2];
    const float* user_tab      = (const float*)d_in[3];
    const float* item_tab      = (const float*)d_in[4];
    const float* W2_tab        = (const float*)d_in[5];
    const float* b2_tab        = (const float*)d_in[6];
    const float* fg_item_W     = (const float*)d_in[7];
    const float* fg_item_b     = (const float*)d_in[8];
    const float* fg_user_W     = (const float*)d_in[9];
    const float* fg_user_b     = (const float*)d_in[10];
    const float* igi           = (const float*)d_in[11];
    const float* igu           = (const float*)d_in[12];
    float* out = (float*)d_out;

    const size_t need = (size_t)3 * NB * DD * sizeof(float);   // 3 MB
    if (ws_size >= need) {
        float* ufg_ws = (float*)d_ws;
        float* t2_ws  = ufg_ws + NB * DD;
        float* v_ws   = t2_ws + NB * DD;
        k0_user<<<NB / 16, 64, 0, stream>>>(user_ids, user_tab, fg_user_W,
                                            fg_user_b, fg_item_b, igu, ufg_ws, t2_ws);
        k1_union<<<NB / 4, 256, 0, stream>>>(user_ids, item_seq_ids, user_tab,
                                             item_tab, fg_item_W, igi, ufg_ws,
                                             t2_ws, v_ws);
        k2_score<<<NB, 256, 0, stream>>>(target_item_ids, W2_tab, b2_tab, v_ws, out);
    } else {
        hgn_fused<<<NB, 256, 0, stream>>>(user_ids, item_seq_ids, target_item_ids,
                                          user_tab, item_tab, W2_tab, b2_tab,
                                          fg_item_W, fg_item_b, fg_user_W, fg_user_b,
                                          igi, igu, out);
    }
}

// Round 6
// 161.080 us; speedup vs baseline: 1.2934x; 1.0036x over previous
//
#include <hip/hip_runtime.h>

// Problem constants
#define DD 64
#define LL 50
#define NB 4096
#define NT 100

typedef __attribute__((ext_vector_type(8))) __bf16 bf16x8;
typedef __attribute__((ext_vector_type(4))) float f32x4;

__device__ __forceinline__ float sigmoidf_(float x) {
    return 1.0f / (1.0f + __expf(-x));
}
__device__ __forceinline__ float b2f(unsigned short h) {
    union { unsigned int u; float f; } v; v.u = ((unsigned int)h) << 16; return v.f;
}
// round-half-up f32->bf16, pack two into one u32 (hi -> upper 16)
__device__ __forceinline__ unsigned pack_bf16(float hi, float lo) {
    union { float f; unsigned u; } a, b;
    a.f = hi; b.f = lo;
    return ((a.u + 0x8000u) & 0xffff0000u) | ((b.u + 0x8000u) >> 16);
}
__device__ __forceinline__ uint4 cvt8u(const float* f) {
    uint4 r;
    r.x = pack_bf16(f[1], f[0]);
    r.y = pack_bf16(f[3], f[2]);
    r.z = pack_bf16(f[5], f[4]);
    r.w = pack_bf16(f[7], f[6]);
    return r;
}
__device__ __forceinline__ bf16x8 cvt8(const float* f) {
    return __builtin_bit_cast(bf16x8, cvt8u(f));
}

// ===========================================================================
// K0: batched user GEMM. A = U[16 users x 64], B = [Wu^T (n<64) | igu (n=64+l)].
// One wave per 16 users; grid 256. ufg gets both biases folded.
// ===========================================================================
__global__ __launch_bounds__(64) void k0_user(
    const int* __restrict__ uid_g, const float* __restrict__ user_table,
    const float* __restrict__ Wu, const float* __restrict__ bu,
    const float* __restrict__ bi, const float* __restrict__ igu,
    float* __restrict__ ufg_ws, float* __restrict__ t2_ws)
{
    const int lane = threadIdx.x;
    const int c = lane & 15, q = lane >> 4;
    const int uid = uid_g[blockIdx.x * 16 + c];
    const float* urow = user_table + (size_t)uid * DD;

    bf16x8 af[2];
#pragma unroll
    for (int kf = 0; kf < 2; kf++) {
        float tmp[8];
        *(float4*)&tmp[0] = *(const float4*)(urow + kf * 32 + q * 8);
        *(float4*)&tmp[4] = *(const float4*)(urow + kf * 32 + q * 8 + 4);
        af[kf] = cvt8(tmp);
    }

#pragma unroll
    for (int ni = 0; ni < 8; ni++) {
        f32x4 a = {0.f, 0.f, 0.f, 0.f};
#pragma unroll
        for (int kf = 0; kf < 2; kf++) {
            const int k0 = kf * 32 + q * 8;
            float tmp[8];
            if (ni < 4) {
                const float* src = Wu + (ni * 16 + c) * DD + k0;
                *(float4*)&tmp[0] = *(const float4*)src;
                *(float4*)&tmp[4] = *(const float4*)(src + 4);
            } else {
                const int l = ni * 16 + c - 64;
#pragma unroll
                for (int j = 0; j < 8; j++)
                    tmp[j] = (l < LL) ? igu[(k0 + j) * LL + l] : 0.f;
            }
            a = __builtin_amdgcn_mfma_f32_16x16x32_bf16(af[kf], cvt8(tmp), a, 0, 0, 0);
        }
        const int n = ni * 16 + c;
#pragma unroll
        for (int reg = 0; reg < 4; reg++) {
            const int bo = blockIdx.x * 16 + q * 4 + reg;
            if (n < DD)           ufg_ws[bo * DD + n] = a[reg] + bu[n] + bi[n];
            else if (n < DD + LL) t2_ws[bo * DD + (n - DD)] = a[reg];
        }
    }
}

// ===========================================================================
// K1: union vector, one WAVE per b (4 b per 256-thread block), one barrier.
// Wi staged to LDS bf16 per block; E gathered to A-frags + bf16 LDS slab;
// t2 staged to LDS (1 coalesced VMEM instead of 16 scalar loads/lane).
// ===========================================================================
__global__ __launch_bounds__(256) void k1_union(
    const int* __restrict__ uid_g, const int* __restrict__ iid_g,
    const float* __restrict__ user_table, const float* __restrict__ item_table,
    const float* __restrict__ Wi, const float* __restrict__ igi,
    const float* __restrict__ ufg_ws, const float* __restrict__ t2_ws,
    float* __restrict__ v_ws)
{
    const int tid = threadIdx.x;
    const int w = tid >> 6, lane = tid & 63;
    const int c = lane & 15, q = lane >> 4;
    const int b = blockIdx.x * 4 + w;

    __shared__ unsigned short sE[4][LL][72];   // bf16, row stride 72 hw (144 B)
    __shared__ unsigned short sW[DD][72];      // Wi bf16
    __shared__ float sT[4][DD];                // t2 per wave (50 valid)

    // stage Wi -> LDS (coalesced: 4 threads per row)
    {
        const int n = tid >> 2, ch = tid & 3;
        float tmp[16];
        const float* src = Wi + n * DD + ch * 16;
        *(float4*)&tmp[0]  = *(const float4*)(src);
        *(float4*)&tmp[4]  = *(const float4*)(src + 4);
        *(float4*)&tmp[8]  = *(const float4*)(src + 8);
        *(float4*)&tmp[12] = *(const float4*)(src + 12);
        *(uint4*)&sW[n][ch * 16]     = cvt8u(tmp);
        *(uint4*)&sW[n][ch * 16 + 8] = cvt8u(tmp + 8);
    }

    // stage t2 (wave-private; coalesced 64-lane read)
    sT[w][lane] = t2_ws[b * DD + lane];

    // gather E rows -> A-frags + LDS slab (wave-private)
    const int* iid = iid_g + b * LL;
    bf16x8 ea[4][2];
#pragma unroll
    for (int mi = 0; mi < 4; mi++) {
        const int l = mi * 16 + c;
        if (l < LL) {
            const float* src = item_table + (size_t)iid[l] * DD;
#pragma unroll
            for (int kf = 0; kf < 2; kf++) {
                float tmp[8];
                *(float4*)&tmp[0] = *(const float4*)(src + kf * 32 + q * 8);
                *(float4*)&tmp[4] = *(const float4*)(src + kf * 32 + q * 8 + 4);
                uint4 p = cvt8u(tmp);
                ea[mi][kf] = __builtin_bit_cast(bf16x8, p);
                *(uint4*)&sE[w][l][kf * 32 + q * 8] = p;
            }
        } else {
            uint4 z = {0u, 0u, 0u, 0u};
            ea[mi][0] = __builtin_bit_cast(bf16x8, z);
            ea[mi][1] = __builtin_bit_cast(bf16x8, z);
        }
    }
    __syncthreads();   // sW ready (sE/sT wave-private, also done)

    bf16x8 wb[4][2];
#pragma unroll
    for (int ni = 0; ni < 4; ni++)
#pragma unroll
        for (int kf = 0; kf < 2; kf++)
            wb[ni][kf] = __builtin_bit_cast(bf16x8,
                *(const uint4*)&sW[ni * 16 + c][kf * 32 + q * 8]);

    float ufg4[4], igi4[4];
#pragma unroll
    for (int ni = 0; ni < 4; ni++) {
        ufg4[ni] = ufg_ws[b * DD + ni * 16 + c];
        igi4[ni] = igi[ni * 16 + c];
    }

    float unum[4] = {0.f, 0.f, 0.f, 0.f};
    float sip[4]  = {0.f, 0.f, 0.f, 0.f};
    float isum = 0.f;

#pragma unroll
    for (int mi = 0; mi < 4; mi++) {
        f32x4 acc[4];
#pragma unroll
        for (int ni = 0; ni < 4; ni++) {
            f32x4 a = {0.f, 0.f, 0.f, 0.f};
            a = __builtin_amdgcn_mfma_f32_16x16x32_bf16(ea[mi][0], wb[ni][0], a, 0, 0, 0);
            a = __builtin_amdgcn_mfma_f32_16x16x32_bf16(ea[mi][1], wb[ni][1], a, 0, 0, 0);
            acc[ni] = a;
        }
        float gated[4][4], inst_r[4];
#pragma unroll
        for (int reg = 0; reg < 4; reg++) {
            const int l = mi * 16 + q * 4 + reg;
            const int valid = (l < LL);
            const int lc = valid ? l : 0;
            const float lm = valid ? 1.f : 0.f;
            float t1 = 0.f;
#pragma unroll
            for (int ni = 0; ni < 4; ni++) {
                const float e = b2f(sE[w][lc][ni * 16 + c]) * lm;
                const float g = sigmoidf_(acc[ni][reg] + ufg4[ni]);
                const float gd = e * g;
                gated[reg][ni] = gd;
                t1 += gd * igi4[ni];
                sip[ni] += e;
            }
            t1 += __shfl_xor(t1, 1); t1 += __shfl_xor(t1, 2);
            t1 += __shfl_xor(t1, 4); t1 += __shfl_xor(t1, 8);
            inst_r[reg] = valid ? sigmoidf_(t1 + sT[w][lc]) : 0.f;
        }
#pragma unroll
        for (int reg = 0; reg < 4; reg++) {
            isum += inst_r[reg];
#pragma unroll
            for (int ni = 0; ni < 4; ni++)
                unum[ni] += gated[reg][ni] * inst_r[reg];
        }
    }

#pragma unroll
    for (int ni = 0; ni < 4; ni++) {
        unum[ni] += __shfl_xor(unum[ni], 16); unum[ni] += __shfl_xor(unum[ni], 32);
        sip[ni]  += __shfl_xor(sip[ni], 16);  sip[ni]  += __shfl_xor(sip[ni], 32);
    }
    isum += __shfl_xor(isum, 16); isum += __shfl_xor(isum, 32);

    const float un = (q == 0) ? unum[0] : (q == 1) ? unum[1] : (q == 2) ? unum[2] : unum[3];
    const float si = (q == 0) ? sip[0]  : (q == 1) ? sip[1]  : (q == 2) ? sip[2]  : sip[3];
    const int uid = uid_g[b];
    const float u = user_table[(size_t)uid * DD + lane];
    v_ws[b * DD + lane] = u + un / isum + si;
}

// ===========================================================================
// K2: streaming scores. One block per b; 16 lanes per (b,t), one float4/lane
// (perfectly coalesced 256 B per row request). ids + results staged in LDS.
// ===========================================================================
__global__ __launch_bounds__(256) void k2_score(
    const int* __restrict__ tgt_g, const float* __restrict__ W2,
    const float* __restrict__ b2, const float* __restrict__ v_ws,
    float* __restrict__ out)
{
    const int b = blockIdx.x;
    const int tid = threadIdx.x;
    __shared__ float sv[DD];
    __shared__ int sids[NT];
    __shared__ float sout[NT + 12];   // padded to 112

    if (tid < DD) sv[tid] = v_ws[b * DD + tid];
    if (tid < NT) sids[tid] = tgt_g[b * NT + tid];
    __syncthreads();

    const int j = tid & 15, g = tid >> 4;   // 16 groups of 16 lanes
    float4 vr = *(const float4*)&sv[j * 4];

#pragma unroll
    for (int it = 0; it < 7; it++) {
        const int t = it * 16 + g;
        if (t < NT) {
            const int id = sids[t];
            float4 wv = *(const float4*)(W2 + (size_t)id * DD + j * 4);
            float s = wv.x * vr.x + wv.y * vr.y + wv.z * vr.z + wv.w * vr.w;
            s += __shfl_xor(s, 1);
            s += __shfl_xor(s, 2);
            s += __shfl_xor(s, 4);
            s += __shfl_xor(s, 8);
            if (j == 0) sout[t] = s + b2[id];
        }
    }
    __syncthreads();
    if (tid < NT) out[b * NT + tid] = sout[tid];
}

// ===========================================================================
extern "C" void kernel_launch(void* const* d_in, const int* in_sizes, int n_in,
                              void* d_out, int out_size, void* d_ws, size_t ws_size,
                              hipStream_t stream)
{
    const int* user_ids        = (const int*)d_in[0];
    const int* item_seq_ids    = (const int*)d_in[1];
    const int* target_item_ids = (const int*)d_in[2];
    const float* user_tab      = (const float*)d_in[3];
    const float* item_tab      = (const float*)d_in[4];
    const float* W2_tab        = (const float*)d_in[5];
    const float* b2_tab        = (const float*)d_in[6];
    const float* fg_item_W     = (const float*)d_in[7];
    const float* fg_item_b     = (const float*)d_in[8];
    const float* fg_user_W     = (const float*)d_in[9];
    const float* fg_user_b     = (const float*)d_in[10];
    const float* igi           = (const float*)d_in[11];
    const float* igu           = (const float*)d_in[12];
    float* out = (float*)d_out;

    float* ufg_ws = (float*)d_ws;              // [4096][64]
    float* t2_ws  = ufg_ws + NB * DD;          // [4096][64] (cols 0..49 used)
    float* v_ws   = t2_ws + NB * DD;           // [4096][64]

    k0_user<<<NB / 16, 64, 0, stream>>>(user_ids, user_tab, fg_user_W,
                                        fg_user_b, fg_item_b, igu, ufg_ws, t2_ws);
    k1_union<<<NB / 4, 256, 0, stream>>>(user_ids, item_seq_ids, user_tab,
                                         item_tab, fg_item_W, igi, ufg_ws,
                                         t2_ws, v_ws);
    k2_score<<<NB, 256, 0, stream>>>(target_item_ids, W2_tab, b2_tab, v_ws, out);
}